// Round 9
// baseline (450.261 us; speedup 1.0000x reference)
//
#include <hip/hip_runtime.h>
#include <stdint.h>

#define NS 64      // samples
#define NA 256     // assets
#define NC 8       // clusters
#define NI 10      // inits
#define MAXIT 30   // lloyd iterations
#define MLDS 90    // solve: max cluster size for LDS-resident elimination

typedef unsigned int u32;
typedef unsigned long long u64;

struct Key { u32 x, y; };

// Threefry-2x32, 20 rounds — exact JAX semantics.
__device__ __forceinline__ void tf2x32(u32 k0, u32 k1, u32 c0, u32 c1, u32& o0, u32& o1) {
  u32 ks0 = k0, ks1 = k1, ks2 = k0 ^ k1 ^ 0x1BD11BDAu;
  u32 x0 = c0 + ks0, x1 = c1 + ks1;
#define TFR(r) { x0 += x1; x1 = (x1 << (r)) | (x1 >> (32 - (r))); x1 ^= x0; }
  TFR(13) TFR(15) TFR(26) TFR(6)
  x0 += ks1; x1 += ks2 + 1u;
  TFR(17) TFR(29) TFR(16) TFR(24)
  x0 += ks2; x1 += ks0 + 2u;
  TFR(13) TFR(15) TFR(26) TFR(6)
  x0 += ks0; x1 += ks1 + 3u;
  TFR(17) TFR(29) TFR(16) TFR(24)
  x0 += ks1; x1 += ks2 + 4u;
  TFR(13) TFR(15) TFR(26) TFR(6)
  x0 += ks2; x1 += ks0 + 5u;
#undef TFR
  o0 = x0; o1 = x1;
}

// jax_threefry_partitionable=True semantics (verified round 2):
// split(key, n)[j]              = threefry2x32(key, 0, j) -> (o0, o1)
// random_bits(key, 32, (n,))[i] = o0 ^ o1 of threefry2x32(key, 0, i)
__device__ __forceinline__ Key key_row(Key k, u32 j) {
  Key r; tf2x32(k.x, k.y, 0u, j, r.x, r.y); return r;
}
__device__ __forceinline__ u32 rbits32(Key k, u32 i) {
  u32 o0, o1; tf2x32(k.x, k.y, 0u, i, o0, o1); return o0 ^ o1;
}

// ---------------- Gram G = corr * corr^T (f64), triangle-only, fused diag ------------
__global__ __launch_bounds__(256) void nco_gram_kernel(
    const float* __restrict__ cov, double* __restrict__ G) {
  int b = blockIdx.x;                 // j*10 + tile
  int j = b / 10, tile = b - 10 * j;
  const int TIa[10] = {0,0,0,0,1,1,1,2,2,3};
  const int TJa[10] = {0,1,2,3,1,2,3,2,3,3};
  int ti2 = TIa[tile], tj2 = TJa[tile];
  const float* C = cov + (size_t)j * NA * NA;
  double* Gj = G + (size_t)j * NA * NA;

  __shared__ double sinv[NA];
  __shared__ double As[16][64 + 1];   // As[kk][row]
  __shared__ double Bs[16][64 + 1];
  int t = threadIdx.x;
  int tr = t >> 4, tc = t & 15;       // 16x16 thread tile, each 4x4 out

  sinv[t] = 1.0 / sqrt((double)C[(size_t)t * NA + t]);
  __syncthreads();

  double acc[4][4];
#pragma unroll
  for (int a = 0; a < 4; a++)
#pragma unroll
    for (int bb = 0; bb < 4; bb++) acc[a][bb] = 0.0;

  for (int k0 = 0; k0 < NA; k0 += 16) {
    int kk = t & 15, rr = t >> 4;
    double ck = sinv[k0 + kk];
#pragma unroll
    for (int m = 0; m < 4; m++) {
      int r = rr + 16 * m;
      int gr = ti2 * 64 + r;
      As[kk][r] = (double)C[(size_t)gr * NA + k0 + kk] * sinv[gr] * ck;
      int gc = tj2 * 64 + r;
      Bs[kk][r] = (double)C[(size_t)gc * NA + k0 + kk] * sinv[gc] * ck;
    }
    __syncthreads();
#pragma unroll
    for (int kk2 = 0; kk2 < 16; kk2++) {
      double ar[4], br[4];
#pragma unroll
      for (int m = 0; m < 4; m++) ar[m] = As[kk2][tr + 16 * m];
#pragma unroll
      for (int m = 0; m < 4; m++) br[m] = Bs[kk2][tc + 16 * m];
#pragma unroll
      for (int a = 0; a < 4; a++)
#pragma unroll
        for (int bb = 0; bb < 4; bb++) acc[a][bb] = fma(ar[a], br[bb], acc[a][bb]);
    }
    __syncthreads();
  }
#pragma unroll
  for (int a = 0; a < 4; a++) {
    int gr = ti2 * 64 + tr + 16 * a;
#pragma unroll
    for (int bb = 0; bb < 4; bb++) {
      int gc = tj2 * 64 + tc + 16 * bb;
      Gj[(size_t)gr * NA + gc] = acc[a][bb];
      if (ti2 != tj2) Gj[(size_t)gc * NA + gr] = acc[a][bb];  // symmetry mirror
    }
  }
}

// ---------------- k-means (Gram sums + dirty caching, 4-group sweep, 4 barriers/iter) -
// score_k(t) = S_k/n_k^2 - 2 s_k[t]/n_k with s_k[t] = sum_{i in list_k} G[i][t].
// Unchanged lists (exact ballot compare) skip the sweep -> cached sums bit-exact.
// Exit when NO list changed (== assignment fixed point): bit-exact.
// 4 groups of 256 threads sweep list quarters; S_k reduce lives in wave 0 only.
__global__ __launch_bounds__(1024) void nco_kmeans_kernel(
    const double* __restrict__ G, int* __restrict__ ixsAll,
    double* __restrict__ inertiaAll) {
  int b = blockIdx.x;                 // 0..639
  int xcd = b & 7, s = b >> 3;
  int j  = xcd + 8 * (s / NI);        // sample (bijective XCD swizzle)
  int mi = s - (s / NI) * NI;         // init
  int blk = j * NI + mi;
  int tid = threadIdx.x;
  int t = tid & 255;                  // point / column
  int g = tid >> 8;                   // sweep group 0..3
  int w4 = tid >> 6;                  // wave id (group0 waves: 0..3)
  const double* Gj = G + (size_t)j * NA * NA;

  __shared__ int    li[NC][NA];       // 8 KiB member lists
  __shared__ double sP[4][NC][NA];    // 64 KiB per-group partial s_k[t] (persistent)
  __shared__ int    wcnt[4][NC];
  __shared__ u64    balPrev[4][NC];   // ballots of the CURRENT list contents
  __shared__ u64    balNew[4][NC];
  __shared__ int    nsz[NC];
  __shared__ int    dirty[NC];
  __shared__ double part[NC][8];
  __shared__ double sinvn[NC], ck2[NC];  // persistent across iters
  __shared__ u32    bits[NA];

  // fused init: JAX PRNG chain + stable-rank top-8 (choice without replacement)
  if (g == 0) {
    Key base; base.x = 0u; base.y = 42u;        // jax.random.key(42)
    Key skey = key_row(base, (u32)j);           // split(base, 64)[j]
    Key ikey = key_row(skey, (u32)mi);          // split(skey, 10)[mi]
    Key sub  = key_row(ikey, 1u);               // _shuffle subkey
    bits[t] = rbits32(sub, (u32)t);
  }
  __syncthreads();
  if (g == 0) {
    u32 mine = bits[t];
    int rank = 0;
    for (int u = 0; u < NA; u++) {
      u32 b2 = bits[u];
      rank += (b2 < mine) || (b2 == mine && u < t);
    }
    if (rank < NC) li[rank][0] = t;
    if (t < NC) { nsz[t] = 1; dirty[t] = 1; }
#pragma unroll
    for (int k = 0; k < NC; k++) {                // seed balPrev = singleton ballots
      u64 bal = __ballot(rank == k);
      if ((t & 63) == 0) balPrev[w4][k] = bal;
    }
  }
  __syncthreads();

  double xx = (g == 0) ? Gj[(size_t)t * NA + t] : 0.0;  // ||x_t||^2 (inertia only)
  int myix = -1;
  double fb = 0.0;
  for (int it = 0; it <= MAXIT; ++it) {
    if (it > 0) {
      u64 mybal = 0;
      if (g == 0) {
#pragma unroll
        for (int k = 0; k < NC; k++) {
          u64 bal = __ballot(myix == k);
          if ((t & 63) == 0) { wcnt[w4][k] = (int)__popcll(bal); balNew[w4][k] = bal; }
          if (k == myix) mybal = bal;
        }
      }
      __syncthreads();                 // (A)
      if (g == 0) {
        if (t < NC) {
          int tot = wcnt[0][t] + wcnt[1][t] + wcnt[2][t] + wcnt[3][t];
          if (tot > 0) {
            nsz[t] = tot;
            bool d = (balNew[0][t] != balPrev[0][t]) | (balNew[1][t] != balPrev[1][t]) |
                     (balNew[2][t] != balPrev[2][t]) | (balNew[3][t] != balPrev[3][t]);
            dirty[t] = d ? 1 : 0;
            if (d) {
              balPrev[0][t] = balNew[0][t]; balPrev[1][t] = balNew[1][t];
              balPrev[2][t] = balNew[2][t]; balPrev[3][t] = balNew[3][t];
            }
          } else {
            dirty[t] = 0;              // empty -> frozen list/size/sums (balPrev kept)
          }
        }
        int k = myix;                  // my cluster is non-empty (contains me)
        int base = 0;
        for (int w2 = 0; w2 < w4; w2++) base += wcnt[w2][k];
        li[k][base + (int)__popcll(mybal & ((1ULL << (t & 63)) - 1ULL))] = t;
      }
      __syncthreads();                 // (B)
      // no list changed  <=>  no assignment changed  => fixed point: bit-exact exit
      if (!(dirty[0] | dirty[1] | dirty[2] | dirty[3] |
            dirty[4] | dirty[5] | dirty[6] | dirty[7])) break;
    }

    // quarter sweep over DIRTY clusters (coalesced row reads)
#pragma unroll
    for (int k = 0; k < NC; k++) {
      if (!dirty[k]) continue;
      int n = nsz[k];
      int lo = (g * n) >> 2;
      int hi = ((g + 1) * n) >> 2;
      const int* lk = li[k];
      double a0 = 0.0, a1 = 0.0;
      int i = lo;
      for (; i + 4 <= hi; i += 4) {
        int r0 = lk[i], r1 = lk[i + 1], r2 = lk[i + 2], r3 = lk[i + 3];
        double g0 = Gj[(size_t)r0 * NA + t];
        double g1 = Gj[(size_t)r1 * NA + t];
        double g2 = Gj[(size_t)r2 * NA + t];
        double g3 = Gj[(size_t)r3 * NA + t];
        a0 += g0; a1 += g1; a0 += g2; a1 += g3;
      }
      for (; i < hi; ++i) a0 += Gj[(size_t)lk[i] * NA + t];
      sP[g][k][t] = a0 + a1;
    }
    __syncthreads();                   // (C)

    // S_k for dirty clusters — entirely within wave 0 (wave-ordered LDS)
    if (tid < 64) {
      int k = tid >> 3, r = tid & 7;
      if (dirty[k]) {
        int n = nsz[k];
        double p = 0.0;
        for (int i = r; i < n; i += 8) {
          int q = li[k][i];
          p += sP[0][k][q] + sP[1][k][q] + sP[2][k][q] + sP[3][k][q];
        }
        part[k][r] = p;
      }
      __builtin_amdgcn_wave_barrier();
      if (tid < NC && dirty[tid]) {
        double S = 0.0;
#pragma unroll
        for (int r2 = 0; r2 < 8; r2++) S += part[tid][r2];
        double inn = 1.0 / (double)nsz[tid];
        sinvn[tid] = inn;
        ck2[tid] = S * inn * inn;
      }
    }
    __syncthreads();                   // (F)

    if (g == 0) {
      double sv0 = sP[0][0][t] + sP[1][0][t] + sP[2][0][t] + sP[3][0][t];
      double best = ck2[0] - 2.0 * sv0 * sinvn[0]; int bi = 0;
#pragma unroll
      for (int k = 1; k < NC; k++) {
        double sv = sP[0][k][t] + sP[1][k][t] + sP[2][k][t] + sP[3][k][t];
        double f = ck2[k] - 2.0 * sv * sinvn[k];
        if (f < best) { best = f; bi = k; }   // first-min = jnp.argmin
      }
      fb = best;
      myix = bi;
    }
    // no barrier: next iteration's (A)+(B) fence sP reuse before any rewrite
  }

  __syncthreads();
  if (g == 0) ((double*)sP)[t] = xx + fb;   // scratch: min d^2 of point t
  __syncthreads();
  if (g == 0) ixsAll[blk * NA + t] = myix;
  if (tid == 0) {
    double ss = 0.0;
    for (int i = 0; i < NA; i++) ss += ((double*)sP)[i];   // exact i-order
    inertiaAll[blk] = ss;
  }
}

// ---------------- per-(sample,cluster) masked Markowitz solve ----------------
__global__ __launch_bounds__(256) void nco_csolve_kernel(
    const float* __restrict__ cov, const float* __restrict__ rets,
    const int* __restrict__ ixsAll, const double* __restrict__ inertiaAll,
    double* __restrict__ gbuf_all, double* __restrict__ wc_all) {
  int b = blockIdx.x;                 // j*NC + c
  int j = b >> 3, c = b & 7;
  int t = threadIdx.x, w = t >> 6;
  const float* C = cov + (size_t)j * NA * NA;
  const float* r = rets + (size_t)j * NA;

  __shared__ double bufl[MLDS * MLDS];            // 64.8 KiB
  __shared__ int    li[NA];
  __shared__ int    wcnt[4][NC];
  __shared__ int    scnt[NC];
  __shared__ int    sbest;
  __shared__ double rhs[NA];
  __shared__ double wsub[NA];
  __shared__ double sdenom;

  if (t == 0) {
    double bv = inertiaAll[j * NI]; int bb = 0;
    for (int m = 1; m < NI; m++) {
      double v = inertiaAll[j * NI + m];
      if (v < bv) { bv = v; bb = m; }             // first-min
    }
    sbest = bb;
  }
  __syncthreads();
  const int* ixs = ixsAll + (size_t)(j * NI + sbest) * NA;

  // parallel cluster counts + member list (ascending via ballot/popcount)
  int myc = ixs[t];
  u64 mybal = 0;
#pragma unroll
  for (int u = 0; u < NC; u++) {
    u64 bal = __ballot(myc == u);
    if ((t & 63) == 0) wcnt[w][u] = (int)__popcll(bal);
    if (u == myc) mybal = bal;
  }
  __syncthreads();
  if (t < NC) scnt[t] = wcnt[0][t] + wcnt[1][t] + wcnt[2][t] + wcnt[3][t];
  __syncthreads();
  if (myc == c) {
    int base = 0;
    for (int w2 = 0; w2 < w; w2++) base += wcnt[w2][c];
    li[base + (int)__popcll(mybal & ((1ULL << (t & 63)) - 1ULL))] = t;
  }
  double* wcc = wc_all + ((size_t)j * NC + c) * NA;
  wcc[t] = 0.0;
  __syncthreads();

  int m = scnt[c];
  if (m == 0) return;                  // uniform exit; column stays zero

  if (m <= 64) {
    // ---- single-wave fast path: zero block barriers in the solve ----
    for (int idx = t; idx < m * m; idx += NA) {
      int row = idx / m, col = idx - row * m;
      bufl[idx] = (double)C[(size_t)li[row] * NA + li[col]];
    }
    if (t < m) rhs[t] = (double)r[li[t]];
    __syncthreads();
    if (t < 64) {
      for (int k = 0; k < m - 1; k++) {
        double piv = bufl[k * m + k];
        if (t > k && t < m) {
          double f = bufl[t * m + k] / piv;
          rhs[t] -= f * rhs[k];
          for (int b2 = k + 1; b2 < m; b2++)
            bufl[t * m + b2] -= f * bufl[k * m + b2];
        }
        __builtin_amdgcn_wave_barrier();
      }
      for (int a = m - 1; a >= 0; a--) {
        if (t == a) wsub[a] = rhs[a] / bufl[a * m + a];
        __builtin_amdgcn_wave_barrier();
        if (t < a) rhs[t] -= bufl[t * m + a] * wsub[a];
        __builtin_amdgcn_wave_barrier();
      }
      double ssum = 0.0;                 // redundant per-lane sum (no sync needed)
      for (int a = 0; a < m; a++) ssum += wsub[a];
      if (t < m) wcc[li[t]] = (ssum != 0.0) ? (wsub[t] / ssum) : 0.0;
    }
    return;
  }

  // ---- general path (64 < m), barrier-synced ----
  int soff = 0;
  for (int u = 0; u < c; u++) soff += scnt[u] * scnt[u];  // packed: sum m^2 <= 256^2
  double* bp = (m <= MLDS) ? bufl : (gbuf_all + (size_t)j * NA * NA + soff);

  for (int idx = t; idx < m * m; idx += NA) {
    int row = idx / m, col = idx - row * m;
    bp[idx] = (double)C[(size_t)li[row] * NA + li[col]];
  }
  if (t < m) rhs[t] = (double)r[li[t]];
  __syncthreads();

  for (int k = 0; k < m - 1; k++) {
    double piv = bp[(size_t)k * m + k];
    if (t > k && t < m) {
      double f = bp[(size_t)t * m + k] / piv;
      rhs[t] -= f * rhs[k];
      for (int b2 = k + 1; b2 < m; b2++)
        bp[(size_t)t * m + b2] -= f * bp[(size_t)k * m + b2];
    }
    __syncthreads();
  }
  for (int a = m - 1; a >= 0; a--) {
    if (t == a) wsub[a] = rhs[a] / bp[(size_t)a * m + a];
    __syncthreads();
    if (t < a) rhs[t] -= bp[(size_t)t * m + a] * wsub[a];
    __syncthreads();
  }
  if (t == 0) {
    double ssum = 0.0;
    for (int a = 0; a < m; a++) ssum += wsub[a];
    sdenom = ssum;
  }
  __syncthreads();
  if (t < m) wcc[li[t]] = (sdenom != 0.0) ? (wsub[t] / sdenom) : 0.0;
}

// ---------------- per-sample inter-cluster assembly + output ----------------
__global__ __launch_bounds__(256) void nco_inter_kernel(
    const float* __restrict__ cov, const float* __restrict__ rets,
    const double* __restrict__ wc_all, float* __restrict__ out) {
  int j = blockIdx.x, t = threadIdx.x;
  const float* C = cov + (size_t)j * NA * NA;
  const float* r = rets + (size_t)j * NA;

  __shared__ double wc[NC][NA];
  __shared__ double tmpL[NC][NA];
  __shared__ double interA[NC][NC];
  __shared__ double interb[NC];
  __shared__ double wi[NC];

  for (int c = 0; c < NC; c++) wc[c][t] = wc_all[((size_t)j * NC + c) * NA + t];
  __syncthreads();

  {
    double tcol[NC];
#pragma unroll
    for (int c = 0; c < NC; c++) tcol[c] = 0.0;
    for (int p = 0; p < NA; p++) {
      double cv = (double)C[(size_t)p * NA + t];
#pragma unroll
      for (int c = 0; c < NC; c++) tcol[c] += wc[c][p] * cv;
    }
#pragma unroll
    for (int c = 0; c < NC; c++) tmpL[c][t] = tcol[c];
  }
  __syncthreads();

  if (t < NC * NC) {
    int c = t / NC, c2 = t % NC;
    double s = 0.0;
    for (int q = 0; q < NA; q++) s += tmpL[c][q] * wc[c2][q];
    interA[c][c2] = s;
  }
  if (t >= 64 && t < 64 + NC) {
    int c = t - 64;
    double s = 0.0;
    for (int p = 0; p < NA; p++) s += wc[c][p] * (double)r[p];
    interb[c] = s;
  }
  __syncthreads();

  if (t == 0) {
    double A[NC][NC], bb[NC];
    for (int a = 0; a < NC; a++) {
      bb[a] = interb[a];
      for (int q = 0; q < NC; q++) A[a][q] = interA[a][q];
    }
    for (int k = 0; k < NC; k++) {
      int p = k; double mx = fabs(A[k][k]);
      for (int i2 = k + 1; i2 < NC; i2++) {
        double v = fabs(A[i2][k]);
        if (v > mx) { mx = v; p = i2; }
      }
      if (p != k) {
        for (int q = 0; q < NC; q++) { double tv = A[k][q]; A[k][q] = A[p][q]; A[p][q] = tv; }
        double tb = bb[k]; bb[k] = bb[p]; bb[p] = tb;
      }
      for (int i2 = k + 1; i2 < NC; i2++) {
        double f = A[i2][k] / A[k][k];
        bb[i2] -= f * bb[k];
        for (int q = k + 1; q < NC; q++) A[i2][q] -= f * A[k][q];
      }
    }
    double w[NC];
    for (int a = NC - 1; a >= 0; a--) {
      double s = bb[a];
      for (int q = a + 1; q < NC; q++) s -= A[a][q] * w[q];
      w[a] = s / A[a][a];
    }
    double ssum = 0.0;
    for (int a = 0; a < NC; a++) ssum += w[a];
    for (int a = 0; a < NC; a++) wi[a] = w[a] / ssum;
  }
  __syncthreads();

  double o = 0.0;
#pragma unroll
  for (int c = 0; c < NC; c++) o += wc[c][t] * wi[c];
  out[(size_t)j * NA + t] = (float)o;
}

extern "C" void kernel_launch(void* const* d_in, const int* in_sizes, int n_in,
                              void* d_out, int out_size, void* d_ws, size_t ws_size,
                              hipStream_t stream) {
  const float* cov  = (const float*)d_in[0];
  const float* rets = (const float*)d_in[1];
  float* out = (float*)d_out;
  char* ws = (char*)d_ws;

  const size_t g_bytes = (size_t)NS * NA * NA * sizeof(double);        // 32 MiB
  double* G          = (double*)(ws);
  double* inertiaAll = (double*)(ws + g_bytes);                        // 5 KiB
  int*    ixsAll     = (int*)   (ws + g_bytes + 5120);                 // 640 KiB
  double* wc_all     = (double*)(ws + g_bytes + 5120 + 655360);        // 1 MiB
  double* gbuf_all   = G;       // alias: G dead after kmeans

  hipLaunchKernelGGL(nco_gram_kernel,   dim3(NS * 10), dim3(NA),   0, stream, cov, G);
  hipLaunchKernelGGL(nco_kmeans_kernel, dim3(NS * NI), dim3(1024), 0, stream,
                     G, ixsAll, inertiaAll);
  hipLaunchKernelGGL(nco_csolve_kernel, dim3(NS * NC), dim3(NA),   0, stream,
                     cov, rets, ixsAll, inertiaAll, gbuf_all, wc_all);
  hipLaunchKernelGGL(nco_inter_kernel,  dim3(NS),      dim3(NA),   0, stream,
                     cov, rets, wc_all, out);
}

// Round 10
// 390.516 us; speedup vs baseline: 1.1530x; 1.1530x over previous
//
#include <hip/hip_runtime.h>
#include <stdint.h>

#define NS 64      // samples
#define NA 256     // assets
#define NC 8       // clusters
#define NI 10      // inits
#define MAXIT 30   // lloyd iterations
#define MLDS 90    // solve: max cluster size for LDS-resident elimination

typedef unsigned int u32;
typedef unsigned long long u64;

struct Key { u32 x, y; };

// Threefry-2x32, 20 rounds — exact JAX semantics.
__device__ __forceinline__ void tf2x32(u32 k0, u32 k1, u32 c0, u32 c1, u32& o0, u32& o1) {
  u32 ks0 = k0, ks1 = k1, ks2 = k0 ^ k1 ^ 0x1BD11BDAu;
  u32 x0 = c0 + ks0, x1 = c1 + ks1;
#define TFR(r) { x0 += x1; x1 = (x1 << (r)) | (x1 >> (32 - (r))); x1 ^= x0; }
  TFR(13) TFR(15) TFR(26) TFR(6)
  x0 += ks1; x1 += ks2 + 1u;
  TFR(17) TFR(29) TFR(16) TFR(24)
  x0 += ks2; x1 += ks0 + 2u;
  TFR(13) TFR(15) TFR(26) TFR(6)
  x0 += ks0; x1 += ks1 + 3u;
  TFR(17) TFR(29) TFR(16) TFR(24)
  x0 += ks1; x1 += ks2 + 4u;
  TFR(13) TFR(15) TFR(26) TFR(6)
  x0 += ks2; x1 += ks0 + 5u;
#undef TFR
  o0 = x0; o1 = x1;
}

// jax_threefry_partitionable=True semantics (verified round 2):
// split(key, n)[j]              = threefry2x32(key, 0, j) -> (o0, o1)
// random_bits(key, 32, (n,))[i] = o0 ^ o1 of threefry2x32(key, 0, i)
__device__ __forceinline__ Key key_row(Key k, u32 j) {
  Key r; tf2x32(k.x, k.y, 0u, j, r.x, r.y); return r;
}
__device__ __forceinline__ u32 rbits32(Key k, u32 i) {
  u32 o0, o1; tf2x32(k.x, k.y, 0u, i, o0, o1); return o0 ^ o1;
}

// ---------------- Gram G = corr * corr^T (f64), triangle-only, fused diag ------------
__global__ __launch_bounds__(256) void nco_gram_kernel(
    const float* __restrict__ cov, double* __restrict__ G) {
  int b = blockIdx.x;                 // j*10 + tile
  int j = b / 10, tile = b - 10 * j;
  const int TIa[10] = {0,0,0,0,1,1,1,2,2,3};
  const int TJa[10] = {0,1,2,3,1,2,3,2,3,3};
  int ti2 = TIa[tile], tj2 = TJa[tile];
  const float* C = cov + (size_t)j * NA * NA;
  double* Gj = G + (size_t)j * NA * NA;

  __shared__ double sinv[NA];
  __shared__ double As[16][64 + 1];   // As[kk][row]
  __shared__ double Bs[16][64 + 1];
  int t = threadIdx.x;
  int tr = t >> 4, tc = t & 15;       // 16x16 thread tile, each 4x4 out

  sinv[t] = 1.0 / sqrt((double)C[(size_t)t * NA + t]);
  __syncthreads();

  double acc[4][4];
#pragma unroll
  for (int a = 0; a < 4; a++)
#pragma unroll
    for (int bb = 0; bb < 4; bb++) acc[a][bb] = 0.0;

  for (int k0 = 0; k0 < NA; k0 += 16) {
    int kk = t & 15, rr = t >> 4;
    double ck = sinv[k0 + kk];
#pragma unroll
    for (int m = 0; m < 4; m++) {
      int r = rr + 16 * m;
      int gr = ti2 * 64 + r;
      As[kk][r] = (double)C[(size_t)gr * NA + k0 + kk] * sinv[gr] * ck;
      int gc = tj2 * 64 + r;
      Bs[kk][r] = (double)C[(size_t)gc * NA + k0 + kk] * sinv[gc] * ck;
    }
    __syncthreads();
#pragma unroll
    for (int kk2 = 0; kk2 < 16; kk2++) {
      double ar[4], br[4];
#pragma unroll
      for (int m = 0; m < 4; m++) ar[m] = As[kk2][tr + 16 * m];
#pragma unroll
      for (int m = 0; m < 4; m++) br[m] = Bs[kk2][tc + 16 * m];
#pragma unroll
      for (int a = 0; a < 4; a++)
#pragma unroll
        for (int bb = 0; bb < 4; bb++) acc[a][bb] = fma(ar[a], br[bb], acc[a][bb]);
    }
    __syncthreads();
  }
#pragma unroll
  for (int a = 0; a < 4; a++) {
    int gr = ti2 * 64 + tr + 16 * a;
#pragma unroll
    for (int bb = 0; bb < 4; bb++) {
      int gc = tj2 * 64 + tc + 16 * bb;
      Gj[(size_t)gr * NA + gc] = acc[a][bb];
      if (ti2 != tj2) Gj[(size_t)gc * NA + gr] = acc[a][bb];  // symmetry mirror
    }
  }
}

// ---------------- k-means (Gram sums + dirty caching, 512 thr, 4 barriers/iter) ------
// score_k(t) = S_k/n_k^2 - 2 s_k[t]/n_k with s_k[t] = sum_{i in list_k} G[i][t].
// Unchanged lists (exact ballot compare) skip the sweep -> cached sums bit-exact.
// Exit when NO list changed (== assignment fixed point): bit-exact.
// Group 0/1 (256 thr each) sweep list halves; S_k reduce lives in wave 0 only.
__global__ __launch_bounds__(512) void nco_kmeans_kernel(
    const double* __restrict__ G, int* __restrict__ ixsAll,
    double* __restrict__ inertiaAll) {
  int b = blockIdx.x;                 // 0..639
  int xcd = b & 7, s = b >> 3;
  int j  = xcd + 8 * (s / NI);        // sample (bijective XCD swizzle)
  int mi = s - (s / NI) * NI;         // init
  int blk = j * NI + mi;
  int tid = threadIdx.x;
  int t = tid & 255;                  // point / column
  int g = tid >> 8;                   // sweep group 0..1
  int w4 = tid >> 6;                  // wave id (group0 waves: 0..3)
  const double* Gj = G + (size_t)j * NA * NA;

  __shared__ int    li[NC][NA];       // 8 KiB member lists
  __shared__ double sA[NC][NA];       // 16 KiB group-0 partial s_k[t] (persistent)
  __shared__ double sB[NC][NA];       // 16 KiB group-1 partial s_k[t] (persistent)
  __shared__ int    wcnt[4][NC];
  __shared__ u64    balPrev[4][NC];   // ballots of the CURRENT list contents
  __shared__ u64    balNew[4][NC];
  __shared__ int    nsz[NC];
  __shared__ int    dirty[NC];
  __shared__ double part[NC][8];
  __shared__ double sinvn[NC], ck2[NC];  // persistent across iters
  __shared__ u32    bits[NA];

  // fused init: JAX PRNG chain + stable-rank top-8 (choice without replacement)
  if (g == 0) {
    Key base; base.x = 0u; base.y = 42u;        // jax.random.key(42)
    Key skey = key_row(base, (u32)j);           // split(base, 64)[j]
    Key ikey = key_row(skey, (u32)mi);          // split(skey, 10)[mi]
    Key sub  = key_row(ikey, 1u);               // _shuffle subkey
    bits[t] = rbits32(sub, (u32)t);
  }
  __syncthreads();
  if (g == 0) {
    u32 mine = bits[t];
    int rank = 0;
    for (int u = 0; u < NA; u++) {
      u32 b2 = bits[u];
      rank += (b2 < mine) || (b2 == mine && u < t);
    }
    if (rank < NC) li[rank][0] = t;
    if (t < NC) { nsz[t] = 1; dirty[t] = 1; }
#pragma unroll
    for (int k = 0; k < NC; k++) {                // seed balPrev = singleton ballots
      u64 bal = __ballot(rank == k);
      if ((t & 63) == 0) balPrev[w4][k] = bal;
    }
  }
  __syncthreads();

  double xx = (g == 0) ? Gj[(size_t)t * NA + t] : 0.0;  // ||x_t||^2 (inertia only)
  int myix = -1;
  double fb = 0.0;
  for (int it = 0; it <= MAXIT; ++it) {
    if (it > 0) {
      u64 mybal = 0;
      if (g == 0) {
#pragma unroll
        for (int k = 0; k < NC; k++) {
          u64 bal = __ballot(myix == k);
          if ((t & 63) == 0) { wcnt[w4][k] = (int)__popcll(bal); balNew[w4][k] = bal; }
          if (k == myix) mybal = bal;
        }
      }
      __syncthreads();                 // (A)
      if (g == 0) {
        if (t < NC) {
          int tot = wcnt[0][t] + wcnt[1][t] + wcnt[2][t] + wcnt[3][t];
          if (tot > 0) {
            nsz[t] = tot;
            bool d = (balNew[0][t] != balPrev[0][t]) | (balNew[1][t] != balPrev[1][t]) |
                     (balNew[2][t] != balPrev[2][t]) | (balNew[3][t] != balPrev[3][t]);
            dirty[t] = d ? 1 : 0;
            if (d) {
              balPrev[0][t] = balNew[0][t]; balPrev[1][t] = balNew[1][t];
              balPrev[2][t] = balNew[2][t]; balPrev[3][t] = balNew[3][t];
            }
          } else {
            dirty[t] = 0;              // empty -> frozen list/size/sums
          }
        }
        int k = myix;                  // my cluster is non-empty (contains me)
        int base = 0;
        for (int w2 = 0; w2 < w4; w2++) base += wcnt[w2][k];
        li[k][base + (int)__popcll(mybal & ((1ULL << (t & 63)) - 1ULL))] = t;
      }
      __syncthreads();                 // (B)
      // no list changed <=> no assignment changed => fixed point: bit-exact exit
      if (!(dirty[0] | dirty[1] | dirty[2] | dirty[3] |
            dirty[4] | dirty[5] | dirty[6] | dirty[7])) break;
    }

    // half sweep over DIRTY clusters (coalesced row reads)
#pragma unroll
    for (int k = 0; k < NC; k++) {
      if (!dirty[k]) continue;
      int n = nsz[k];
      int nh = n >> 1;
      int lo = g ? nh : 0;
      int hi = g ? n : nh;
      const int* lk = li[k];
      double a0 = 0.0, a1 = 0.0;
      int i = lo;
      for (; i + 4 <= hi; i += 4) {
        int r0 = lk[i], r1 = lk[i + 1], r2 = lk[i + 2], r3 = lk[i + 3];
        double g0 = Gj[(size_t)r0 * NA + t];
        double g1 = Gj[(size_t)r1 * NA + t];
        double g2 = Gj[(size_t)r2 * NA + t];
        double g3 = Gj[(size_t)r3 * NA + t];
        a0 += g0; a1 += g1; a0 += g2; a1 += g3;
      }
      for (; i < hi; ++i) a0 += Gj[(size_t)lk[i] * NA + t];
      if (g) sB[k][t] = a0 + a1; else sA[k][t] = a0 + a1;
    }
    __syncthreads();                   // (C)

    // S_k for dirty clusters — entirely within wave 0 (wave-ordered LDS)
    if (tid < 64) {
      int k = tid >> 3, r = tid & 7;
      if (dirty[k]) {
        int n = nsz[k];
        double p = 0.0;
        for (int i = r; i < n; i += 8) {
          int q = li[k][i];
          p += sA[k][q] + sB[k][q];
        }
        part[k][r] = p;
      }
      __builtin_amdgcn_wave_barrier();
      if (tid < NC && dirty[tid]) {
        double S = 0.0;
#pragma unroll
        for (int r2 = 0; r2 < 8; r2++) S += part[tid][r2];
        double inn = 1.0 / (double)nsz[tid];
        sinvn[tid] = inn;
        ck2[tid] = S * inn * inn;
      }
    }
    __syncthreads();                   // (F)

    if (g == 0) {
      double best = ck2[0] - 2.0 * (sA[0][t] + sB[0][t]) * sinvn[0]; int bi = 0;
#pragma unroll
      for (int k = 1; k < NC; k++) {
        double f = ck2[k] - 2.0 * (sA[k][t] + sB[k][t]) * sinvn[k];
        if (f < best) { best = f; bi = k; }   // first-min = jnp.argmin
      }
      fb = best;
      myix = bi;
    }
    // no barrier: next iteration's (A)+(B) fence sA/sB reuse before any rewrite
  }

  __syncthreads();
  if (g == 0) ((double*)sB)[t] = xx + fb;   // scratch: min d^2 of point t
  __syncthreads();
  if (g == 0) ixsAll[blk * NA + t] = myix;
  if (tid == 0) {
    double ss = 0.0;
    for (int i = 0; i < NA; i++) ss += ((double*)sB)[i];   // exact i-order
    inertiaAll[blk] = ss;
  }
}

// ---------------- per-(sample,cluster) masked Markowitz solve ----------------
// LDS elimination uses ODD row stride ms = m|1: even m made row starts 32-bank
// aligned -> all active lanes on one bank (up to 64-way serialize). Odd stride
// spreads lanes across 16 banks (~4-way for f64, near-free per m136).
__global__ __launch_bounds__(256) void nco_csolve_kernel(
    const float* __restrict__ cov, const float* __restrict__ rets,
    const int* __restrict__ ixsAll, const double* __restrict__ inertiaAll,
    double* __restrict__ gbuf_all, double* __restrict__ wc_all) {
  int b = blockIdx.x;                 // j*NC + c
  int j = b >> 3, c = b & 7;
  int t = threadIdx.x, w = t >> 6;
  const float* C = cov + (size_t)j * NA * NA;
  const float* r = rets + (size_t)j * NA;

  __shared__ double bufl[MLDS * (MLDS + 1)];      // 65.5 KiB (padded stride)
  __shared__ int    li[NA];
  __shared__ int    wcnt[4][NC];
  __shared__ int    scnt[NC];
  __shared__ int    sbest;
  __shared__ double rhs[NA];
  __shared__ double wsub[NA];
  __shared__ double sdenom;

  if (t == 0) {
    double bv = inertiaAll[j * NI]; int bb = 0;
    for (int m = 1; m < NI; m++) {
      double v = inertiaAll[j * NI + m];
      if (v < bv) { bv = v; bb = m; }             // first-min
    }
    sbest = bb;
  }
  __syncthreads();
  const int* ixs = ixsAll + (size_t)(j * NI + sbest) * NA;

  // parallel cluster counts + member list (ascending via ballot/popcount)
  int myc = ixs[t];
  u64 mybal = 0;
#pragma unroll
  for (int u = 0; u < NC; u++) {
    u64 bal = __ballot(myc == u);
    if ((t & 63) == 0) wcnt[w][u] = (int)__popcll(bal);
    if (u == myc) mybal = bal;
  }
  __syncthreads();
  if (t < NC) scnt[t] = wcnt[0][t] + wcnt[1][t] + wcnt[2][t] + wcnt[3][t];
  __syncthreads();
  if (myc == c) {
    int base = 0;
    for (int w2 = 0; w2 < w; w2++) base += wcnt[w2][c];
    li[base + (int)__popcll(mybal & ((1ULL << (t & 63)) - 1ULL))] = t;
  }
  double* wcc = wc_all + ((size_t)j * NC + c) * NA;
  wcc[t] = 0.0;
  __syncthreads();

  int m = scnt[c];
  if (m == 0) return;                  // uniform exit; column stays zero

  if (m <= 64) {
    // ---- single-wave fast path: zero block barriers in the solve ----
    int ms = m | 1;                    // odd stride
    for (int idx = t; idx < m * m; idx += NA) {
      int row = idx / m, col = idx - row * m;
      bufl[row * ms + col] = (double)C[(size_t)li[row] * NA + li[col]];
    }
    if (t < m) rhs[t] = (double)r[li[t]];
    __syncthreads();
    if (t < 64) {
      for (int k = 0; k < m - 1; k++) {
        double piv = bufl[k * ms + k];
        if (t > k && t < m) {
          double f = bufl[t * ms + k] / piv;
          rhs[t] -= f * rhs[k];
          for (int b2 = k + 1; b2 < m; b2++)
            bufl[t * ms + b2] -= f * bufl[k * ms + b2];
        }
        __builtin_amdgcn_wave_barrier();
      }
      for (int a = m - 1; a >= 0; a--) {
        if (t == a) wsub[a] = rhs[a] / bufl[a * ms + a];
        __builtin_amdgcn_wave_barrier();
        if (t < a) rhs[t] -= bufl[t * ms + a] * wsub[a];
        __builtin_amdgcn_wave_barrier();
      }
      double ssum = 0.0;                 // redundant per-lane sum (no sync needed)
      for (int a = 0; a < m; a++) ssum += wsub[a];
      if (t < m) wcc[li[t]] = (ssum != 0.0) ? (wsub[t] / ssum) : 0.0;
    }
    return;
  }

  // ---- block path (64 < m <= MLDS in LDS w/ odd stride; else global) ----
  int inlds = (m <= MLDS);
  int ms = inlds ? (m | 1) : m;
  double* bp;
  if (inlds) {
    bp = bufl;
  } else {
    int soff = 0;
    for (int u = 0; u < c; u++) soff += scnt[u] * scnt[u];  // packed: sum m^2 <= 256^2
    bp = gbuf_all + (size_t)j * NA * NA + soff;
  }

  for (int idx = t; idx < m * m; idx += NA) {
    int row = idx / m, col = idx - row * m;
    bp[(size_t)row * ms + col] = (double)C[(size_t)li[row] * NA + li[col]];
  }
  if (t < m) rhs[t] = (double)r[li[t]];
  __syncthreads();

  for (int k = 0; k < m - 1; k++) {
    double piv = bp[(size_t)k * ms + k];
    if (t > k && t < m) {
      double f = bp[(size_t)t * ms + k] / piv;
      rhs[t] -= f * rhs[k];
      for (int b2 = k + 1; b2 < m; b2++)
        bp[(size_t)t * ms + b2] -= f * bp[(size_t)k * ms + b2];
    }
    __syncthreads();
  }
  for (int a = m - 1; a >= 0; a--) {
    if (t == a) wsub[a] = rhs[a] / bp[(size_t)a * ms + a];
    __syncthreads();
    if (t < a) rhs[t] -= bp[(size_t)t * ms + a] * wsub[a];
    __syncthreads();
  }
  if (t == 0) {
    double ssum = 0.0;
    for (int a = 0; a < m; a++) ssum += wsub[a];
    sdenom = ssum;
  }
  __syncthreads();
  if (t < m) wcc[li[t]] = (sdenom != 0.0) ? (wsub[t] / sdenom) : 0.0;
}

// ---------------- per-sample inter-cluster assembly + output ----------------
__global__ __launch_bounds__(256) void nco_inter_kernel(
    const float* __restrict__ cov, const float* __restrict__ rets,
    const double* __restrict__ wc_all, float* __restrict__ out) {
  int j = blockIdx.x, t = threadIdx.x;
  const float* C = cov + (size_t)j * NA * NA;
  const float* r = rets + (size_t)j * NA;

  __shared__ double wc[NC][NA];
  __shared__ double tmpL[NC][NA];
  __shared__ double interA[NC][NC];
  __shared__ double interb[NC];
  __shared__ double wi[NC];

  for (int c = 0; c < NC; c++) wc[c][t] = wc_all[((size_t)j * NC + c) * NA + t];
  __syncthreads();

  {
    double tcol[NC];
#pragma unroll
    for (int c = 0; c < NC; c++) tcol[c] = 0.0;
    for (int p = 0; p < NA; p++) {
      double cv = (double)C[(size_t)p * NA + t];
#pragma unroll
      for (int c = 0; c < NC; c++) tcol[c] += wc[c][p] * cv;
    }
#pragma unroll
    for (int c = 0; c < NC; c++) tmpL[c][t] = tcol[c];
  }
  __syncthreads();

  if (t < NC * NC) {
    int c = t / NC, c2 = t % NC;
    double s = 0.0;
    for (int q = 0; q < NA; q++) s += tmpL[c][q] * wc[c2][q];
    interA[c][c2] = s;
  }
  if (t >= 64 && t < 64 + NC) {
    int c = t - 64;
    double s = 0.0;
    for (int p = 0; p < NA; p++) s += wc[c][p] * (double)r[p];
    interb[c] = s;
  }
  __syncthreads();

  if (t == 0) {
    double A[NC][NC], bb[NC];
    for (int a = 0; a < NC; a++) {
      bb[a] = interb[a];
      for (int q = 0; q < NC; q++) A[a][q] = interA[a][q];
    }
    for (int k = 0; k < NC; k++) {
      int p = k; double mx = fabs(A[k][k]);
      for (int i2 = k + 1; i2 < NC; i2++) {
        double v = fabs(A[i2][k]);
        if (v > mx) { mx = v; p = i2; }
      }
      if (p != k) {
        for (int q = 0; q < NC; q++) { double tv = A[k][q]; A[k][q] = A[p][q]; A[p][q] = tv; }
        double tb = bb[k]; bb[k] = bb[p]; bb[p] = tb;
      }
      for (int i2 = k + 1; i2 < NC; i2++) {
        double f = A[i2][k] / A[k][k];
        bb[i2] -= f * bb[k];
        for (int q = k + 1; q < NC; q++) A[i2][q] -= f * A[k][q];
      }
    }
    double w[NC];
    for (int a = NC - 1; a >= 0; a--) {
      double s = bb[a];
      for (int q = a + 1; q < NC; q++) s -= A[a][q] * w[q];
      w[a] = s / A[a][a];
    }
    double ssum = 0.0;
    for (int a = 0; a < NC; a++) ssum += w[a];
    for (int a = 0; a < NC; a++) wi[a] = w[a] / ssum;
  }
  __syncthreads();

  double o = 0.0;
#pragma unroll
  for (int c = 0; c < NC; c++) o += wc[c][t] * wi[c];
  out[(size_t)j * NA + t] = (float)o;
}

extern "C" void kernel_launch(void* const* d_in, const int* in_sizes, int n_in,
                              void* d_out, int out_size, void* d_ws, size_t ws_size,
                              hipStream_t stream) {
  const float* cov  = (const float*)d_in[0];
  const float* rets = (const float*)d_in[1];
  float* out = (float*)d_out;
  char* ws = (char*)d_ws;

  const size_t g_bytes = (size_t)NS * NA * NA * sizeof(double);        // 32 MiB
  double* G          = (double*)(ws);
  double* inertiaAll = (double*)(ws + g_bytes);                        // 5 KiB
  int*    ixsAll     = (int*)   (ws + g_bytes + 5120);                 // 640 KiB
  double* wc_all     = (double*)(ws + g_bytes + 5120 + 655360);        // 1 MiB
  double* gbuf_all   = G;       // alias: G dead after kmeans

  hipLaunchKernelGGL(nco_gram_kernel,   dim3(NS * 10), dim3(NA),  0, stream, cov, G);
  hipLaunchKernelGGL(nco_kmeans_kernel, dim3(NS * NI), dim3(512), 0, stream,
                     G, ixsAll, inertiaAll);
  hipLaunchKernelGGL(nco_csolve_kernel, dim3(NS * NC), dim3(NA),  0, stream,
                     cov, rets, ixsAll, inertiaAll, gbuf_all, wc_all);
  hipLaunchKernelGGL(nco_inter_kernel,  dim3(NS),      dim3(NA),  0, stream,
                     cov, rets, wc_all, out);
}

// Round 11
// 309.130 us; speedup vs baseline: 1.4565x; 1.2633x over previous
//
#include <hip/hip_runtime.h>
#include <stdint.h>

#define NS 64      // samples
#define NA 256     // assets
#define NC 8       // clusters
#define NI 10      // inits
#define MAXIT 30   // lloyd iterations
#define MLDS 90    // solve: max cluster size for LDS-resident elimination

typedef unsigned int u32;
typedef unsigned long long u64;

struct Key { u32 x, y; };

// Threefry-2x32, 20 rounds — exact JAX semantics.
__device__ __forceinline__ void tf2x32(u32 k0, u32 k1, u32 c0, u32 c1, u32& o0, u32& o1) {
  u32 ks0 = k0, ks1 = k1, ks2 = k0 ^ k1 ^ 0x1BD11BDAu;
  u32 x0 = c0 + ks0, x1 = c1 + ks1;
#define TFR(r) { x0 += x1; x1 = (x1 << (r)) | (x1 >> (32 - (r))); x1 ^= x0; }
  TFR(13) TFR(15) TFR(26) TFR(6)
  x0 += ks1; x1 += ks2 + 1u;
  TFR(17) TFR(29) TFR(16) TFR(24)
  x0 += ks2; x1 += ks0 + 2u;
  TFR(13) TFR(15) TFR(26) TFR(6)
  x0 += ks0; x1 += ks1 + 3u;
  TFR(17) TFR(29) TFR(16) TFR(24)
  x0 += ks1; x1 += ks2 + 4u;
  TFR(13) TFR(15) TFR(26) TFR(6)
  x0 += ks2; x1 += ks0 + 5u;
#undef TFR
  o0 = x0; o1 = x1;
}

// jax_threefry_partitionable=True semantics (verified round 2):
// split(key, n)[j]              = threefry2x32(key, 0, j) -> (o0, o1)
// random_bits(key, 32, (n,))[i] = o0 ^ o1 of threefry2x32(key, 0, i)
__device__ __forceinline__ Key key_row(Key k, u32 j) {
  Key r; tf2x32(k.x, k.y, 0u, j, r.x, r.y); return r;
}
__device__ __forceinline__ u32 rbits32(Key k, u32 i) {
  u32 o0, o1; tf2x32(k.x, k.y, 0u, i, o0, o1); return o0 ^ o1;
}

// ---------------- Gram G = corr * corr^T (f64), triangle-only, fused diag ------------
__global__ __launch_bounds__(256) void nco_gram_kernel(
    const float* __restrict__ cov, double* __restrict__ G) {
  int b = blockIdx.x;                 // j*10 + tile
  int j = b / 10, tile = b - 10 * j;
  const int TIa[10] = {0,0,0,0,1,1,1,2,2,3};
  const int TJa[10] = {0,1,2,3,1,2,3,2,3,3};
  int ti2 = TIa[tile], tj2 = TJa[tile];
  const float* C = cov + (size_t)j * NA * NA;
  double* Gj = G + (size_t)j * NA * NA;

  __shared__ double sinv[NA];
  __shared__ double As[16][64 + 1];   // As[kk][row]
  __shared__ double Bs[16][64 + 1];
  int t = threadIdx.x;
  int tr = t >> 4, tc = t & 15;       // 16x16 thread tile, each 4x4 out

  sinv[t] = 1.0 / sqrt((double)C[(size_t)t * NA + t]);
  __syncthreads();

  double acc[4][4];
#pragma unroll
  for (int a = 0; a < 4; a++)
#pragma unroll
    for (int bb = 0; bb < 4; bb++) acc[a][bb] = 0.0;

  for (int k0 = 0; k0 < NA; k0 += 16) {
    int kk = t & 15, rr = t >> 4;
    double ck = sinv[k0 + kk];
#pragma unroll
    for (int m = 0; m < 4; m++) {
      int r = rr + 16 * m;
      int gr = ti2 * 64 + r;
      As[kk][r] = (double)C[(size_t)gr * NA + k0 + kk] * sinv[gr] * ck;
      int gc = tj2 * 64 + r;
      Bs[kk][r] = (double)C[(size_t)gc * NA + k0 + kk] * sinv[gc] * ck;
    }
    __syncthreads();
#pragma unroll
    for (int kk2 = 0; kk2 < 16; kk2++) {
      double ar[4], br[4];
#pragma unroll
      for (int m = 0; m < 4; m++) ar[m] = As[kk2][tr + 16 * m];
#pragma unroll
      for (int m = 0; m < 4; m++) br[m] = Bs[kk2][tc + 16 * m];
#pragma unroll
      for (int a = 0; a < 4; a++)
#pragma unroll
        for (int bb = 0; bb < 4; bb++) acc[a][bb] = fma(ar[a], br[bb], acc[a][bb]);
    }
    __syncthreads();
  }
#pragma unroll
  for (int a = 0; a < 4; a++) {
    int gr = ti2 * 64 + tr + 16 * a;
#pragma unroll
    for (int bb = 0; bb < 4; bb++) {
      int gc = tj2 * 64 + tc + 16 * bb;
      Gj[(size_t)gr * NA + gc] = acc[a][bb];
      if (ti2 != tj2) Gj[(size_t)gc * NA + gr] = acc[a][bb];  // symmetry mirror
    }
  }
}

// ---------------- k-means (incremental Gram sums via ballot diffs) -------------------
// s_k[t] = sum_{i in list_k} G[i][t] kept in LDS across iterations; updated by
// the exact membership diff (balNew ^ balPrev): s -= removed rows, += added
// rows. Frozen-empty semantics: empty cluster keeps balPrev = its defining
// list, so a later re-fill diffs against exactly that list. Exit when no list
// changed (assignment fixed point). Deterministic fixed-order updates.
// Group parity: group g updates clusters with (k&1)==g (no write races).
__global__ __launch_bounds__(512) void nco_kmeans_kernel(
    const double* __restrict__ G, int* __restrict__ ixsAll,
    double* __restrict__ inertiaAll) {
  int b = blockIdx.x;                 // 0..639
  int xcd = b & 7, s0 = b >> 3;
  int j  = xcd + 8 * (s0 / NI);       // sample (bijective XCD swizzle)
  int mi = s0 - (s0 / NI) * NI;       // init
  int blk = j * NI + mi;
  int tid = threadIdx.x;
  int t = tid & 255;                  // point / column
  int g = tid >> 8;                   // group 0..1
  int w4 = tid >> 6;                  // wave id (group0 waves: 0..3)
  const double* Gj = G + (size_t)j * NA * NA;

  __shared__ int    li[NC][NA];       // 8 KiB member lists
  __shared__ double sv[NC][NA];       // 16 KiB s_k[t] (persistent)
  __shared__ int    wcnt[4][NC];
  __shared__ u64    balPrev[4][NC];   // ballots of CURRENT list contents
  __shared__ u64    balNew[4][NC];
  __shared__ u64    dAdd[4][NC];      // diff masks (valid when dirty)
  __shared__ u64    dRem[4][NC];
  __shared__ int    nsz[NC];
  __shared__ int    dirty[NC];
  __shared__ double part[NC][8];
  __shared__ double sinvn[NC], ck2[NC];  // persistent across iters
  __shared__ u32    bits[NA];

  // fused init: JAX PRNG chain + stable-rank top-8 (choice without replacement)
  if (g == 0) {
    Key base; base.x = 0u; base.y = 42u;        // jax.random.key(42)
    Key skey = key_row(base, (u32)j);           // split(base, 64)[j]
    Key ikey = key_row(skey, (u32)mi);          // split(skey, 10)[mi]
    Key sub  = key_row(ikey, 1u);               // _shuffle subkey
    bits[t] = rbits32(sub, (u32)t);
  }
  __syncthreads();
  if (g == 0) {
    u32 mine = bits[t];
    int rank = 0;
    for (int u = 0; u < NA; u++) {
      u32 b2 = bits[u];
      rank += (b2 < mine) || (b2 == mine && u < t);
    }
    if (rank < NC) li[rank][0] = t;
    if (t < NC) { nsz[t] = 1; dirty[t] = 1; }
#pragma unroll
    for (int k = 0; k < NC; k++) {                // seed balPrev = singleton ballots
      u64 bal = __ballot(rank == k);
      if ((t & 63) == 0) balPrev[w4][k] = bal;
    }
  }
  __syncthreads();

  double xx = (g == 0) ? Gj[(size_t)t * NA + t] : 0.0;  // ||x_t||^2 (inertia only)
  int myix = -1;
  double fb = 0.0;
  for (int it = 0; it <= MAXIT; ++it) {
    if (it > 0) {
      u64 mybal = 0;
      if (g == 0) {
#pragma unroll
        for (int k = 0; k < NC; k++) {
          u64 bal = __ballot(myix == k);
          if ((t & 63) == 0) { wcnt[w4][k] = (int)__popcll(bal); balNew[w4][k] = bal; }
          if (k == myix) mybal = bal;
        }
      }
      __syncthreads();                 // (A)
      if (g == 0) {
        if (t < NC) {
          int tot = wcnt[0][t] + wcnt[1][t] + wcnt[2][t] + wcnt[3][t];
          if (tot > 0) {
            nsz[t] = tot;
            bool d = (balNew[0][t] != balPrev[0][t]) | (balNew[1][t] != balPrev[1][t]) |
                     (balNew[2][t] != balPrev[2][t]) | (balNew[3][t] != balPrev[3][t]);
            dirty[t] = d ? 1 : 0;
            if (d) {
#pragma unroll
              for (int w2 = 0; w2 < 4; w2++) {
                dAdd[w2][t] = balNew[w2][t] & ~balPrev[w2][t];
                dRem[w2][t] = balPrev[w2][t] & ~balNew[w2][t];
                balPrev[w2][t] = balNew[w2][t];
              }
            }
          } else {
            dirty[t] = 0;              // empty -> frozen list/size/sums (balPrev kept)
          }
        }
        int k = myix;                  // my cluster is non-empty (contains me)
        int base = 0;
        for (int w2 = 0; w2 < w4; w2++) base += wcnt[w2][k];
        li[k][base + (int)__popcll(mybal & ((1ULL << (t & 63)) - 1ULL))] = t;
      }
      __syncthreads();                 // (B)
      // no list changed <=> no assignment changed => fixed point: bit-exact exit
      if (!(dirty[0] | dirty[1] | dirty[2] | dirty[3] |
            dirty[4] | dirty[5] | dirty[6] | dirty[7])) break;

      // incremental update: group g owns clusters with (k&1)==g
      for (int k = g; k < NC; k += 2) {
        if (!dirty[k]) continue;
        double acc = sv[k][t];
#pragma unroll
        for (int wq = 0; wq < 4; wq++) {
          u64 m0 = dRem[wq][k];
          while (m0) {
            int p = (wq << 6) + (int)__builtin_ctzll(m0);
            m0 &= m0 - 1;
            acc -= Gj[(size_t)p * NA + t];
          }
        }
#pragma unroll
        for (int wq = 0; wq < 4; wq++) {
          u64 m0 = dAdd[wq][k];
          while (m0) {
            int p = (wq << 6) + (int)__builtin_ctzll(m0);
            m0 &= m0 - 1;
            acc += Gj[(size_t)p * NA + t];
          }
        }
        sv[k][t] = acc;
      }
    } else {
      // it == 0: seed s with the singleton init rows
      for (int k = g; k < NC; k += 2) {
        int p = li[k][0];
        sv[k][t] = Gj[(size_t)p * NA + t];
      }
    }
    __syncthreads();                   // (C)

    // S_k for dirty clusters — entirely within wave 0 (wave-ordered LDS)
    if (tid < 64) {
      int k = tid >> 3, r = tid & 7;
      if (dirty[k]) {
        int n = nsz[k];
        double p = 0.0;
        for (int i = r; i < n; i += 8) p += sv[k][li[k][i]];
        part[k][r] = p;
      }
      __builtin_amdgcn_wave_barrier();
      if (tid < NC && dirty[tid]) {
        double S = 0.0;
#pragma unroll
        for (int r2 = 0; r2 < 8; r2++) S += part[tid][r2];
        double inn = 1.0 / (double)nsz[tid];
        sinvn[tid] = inn;
        ck2[tid] = S * inn * inn;
      }
    }
    __syncthreads();                   // (F)

    if (g == 0) {
      double best = ck2[0] - 2.0 * sv[0][t] * sinvn[0]; int bi = 0;
#pragma unroll
      for (int k = 1; k < NC; k++) {
        double f = ck2[k] - 2.0 * sv[k][t] * sinvn[k];
        if (f < best) { best = f; bi = k; }   // first-min = jnp.argmin
      }
      fb = best;
      myix = bi;
    }
    // no barrier: next iteration's (A)+(B) fence sv reuse before any rewrite
  }

  __syncthreads();
  double* red = (double*)&li[0][0];    // li dead after loop; reuse as scratch
  if (g == 0) red[t] = xx + fb;        // min d^2 of point t
  __syncthreads();
  if (g == 0) ixsAll[blk * NA + t] = myix;
  if (tid == 0) {
    double ss = 0.0;
    for (int i = 0; i < NA; i++) ss += red[i];   // exact i-order
    inertiaAll[blk] = ss;
  }
}

// ---------------- per-(sample,cluster) masked Markowitz solve ----------------
// LDS elimination uses ODD row stride ms = m|1 (even m puts all lanes on one
// bank). Single-wave fast path for m <= 64 (wave-ordered LDS, no block sync).
__global__ __launch_bounds__(256) void nco_csolve_kernel(
    const float* __restrict__ cov, const float* __restrict__ rets,
    const int* __restrict__ ixsAll, const double* __restrict__ inertiaAll,
    double* __restrict__ gbuf_all, double* __restrict__ wc_all) {
  int b = blockIdx.x;                 // j*NC + c
  int j = b >> 3, c = b & 7;
  int t = threadIdx.x, w = t >> 6;
  const float* C = cov + (size_t)j * NA * NA;
  const float* r = rets + (size_t)j * NA;

  __shared__ double bufl[MLDS * (MLDS + 1)];      // 65.5 KiB (padded stride)
  __shared__ int    li[NA];
  __shared__ int    wcnt[4][NC];
  __shared__ int    scnt[NC];
  __shared__ int    sbest;
  __shared__ double rhs[NA];
  __shared__ double wsub[NA];
  __shared__ double sdenom;

  if (t == 0) {
    double bv = inertiaAll[j * NI]; int bb = 0;
    for (int m = 1; m < NI; m++) {
      double v = inertiaAll[j * NI + m];
      if (v < bv) { bv = v; bb = m; }             // first-min
    }
    sbest = bb;
  }
  __syncthreads();
  const int* ixs = ixsAll + (size_t)(j * NI + sbest) * NA;

  // parallel cluster counts + member list (ascending via ballot/popcount)
  int myc = ixs[t];
  u64 mybal = 0;
#pragma unroll
  for (int u = 0; u < NC; u++) {
    u64 bal = __ballot(myc == u);
    if ((t & 63) == 0) wcnt[w][u] = (int)__popcll(bal);
    if (u == myc) mybal = bal;
  }
  __syncthreads();
  if (t < NC) scnt[t] = wcnt[0][t] + wcnt[1][t] + wcnt[2][t] + wcnt[3][t];
  __syncthreads();
  if (myc == c) {
    int base = 0;
    for (int w2 = 0; w2 < w; w2++) base += wcnt[w2][c];
    li[base + (int)__popcll(mybal & ((1ULL << (t & 63)) - 1ULL))] = t;
  }
  double* wcc = wc_all + ((size_t)j * NC + c) * NA;
  wcc[t] = 0.0;
  __syncthreads();

  int m = scnt[c];
  if (m == 0) return;                  // uniform exit; column stays zero

  if (m <= 64) {
    // ---- single-wave fast path: zero block barriers in the solve ----
    int ms = m | 1;                    // odd stride
    for (int idx = t; idx < m * m; idx += NA) {
      int row = idx / m, col = idx - row * m;
      bufl[row * ms + col] = (double)C[(size_t)li[row] * NA + li[col]];
    }
    if (t < m) rhs[t] = (double)r[li[t]];
    __syncthreads();
    if (t < 64) {
      for (int k = 0; k < m - 1; k++) {
        double piv = bufl[k * ms + k];
        if (t > k && t < m) {
          double f = bufl[t * ms + k] / piv;
          rhs[t] -= f * rhs[k];
          for (int b2 = k + 1; b2 < m; b2++)
            bufl[t * ms + b2] -= f * bufl[k * ms + b2];
        }
        __builtin_amdgcn_wave_barrier();
      }
      for (int a = m - 1; a >= 0; a--) {
        if (t == a) wsub[a] = rhs[a] / bufl[a * ms + a];
        __builtin_amdgcn_wave_barrier();
        if (t < a) rhs[t] -= bufl[t * ms + a] * wsub[a];
        __builtin_amdgcn_wave_barrier();
      }
      double ssum = 0.0;                 // redundant per-lane sum (no sync needed)
      for (int a = 0; a < m; a++) ssum += wsub[a];
      if (t < m) wcc[li[t]] = (ssum != 0.0) ? (wsub[t] / ssum) : 0.0;
    }
    return;
  }

  // ---- block path (64 < m <= MLDS in LDS w/ odd stride; else global) ----
  int inlds = (m <= MLDS);
  int ms = inlds ? (m | 1) : m;
  double* bp;
  if (inlds) {
    bp = bufl;
  } else {
    int soff = 0;
    for (int u = 0; u < c; u++) soff += scnt[u] * scnt[u];  // packed: sum m^2 <= 256^2
    bp = gbuf_all + (size_t)j * NA * NA + soff;
  }

  for (int idx = t; idx < m * m; idx += NA) {
    int row = idx / m, col = idx - row * m;
    bp[(size_t)row * ms + col] = (double)C[(size_t)li[row] * NA + li[col]];
  }
  if (t < m) rhs[t] = (double)r[li[t]];
  __syncthreads();

  for (int k = 0; k < m - 1; k++) {
    double piv = bp[(size_t)k * ms + k];
    if (t > k && t < m) {
      double f = bp[(size_t)t * ms + k] / piv;
      rhs[t] -= f * rhs[k];
      for (int b2 = k + 1; b2 < m; b2++)
        bp[(size_t)t * ms + b2] -= f * bp[(size_t)k * ms + b2];
    }
    __syncthreads();
  }
  for (int a = m - 1; a >= 0; a--) {
    if (t == a) wsub[a] = rhs[a] / bp[(size_t)a * ms + a];
    __syncthreads();
    if (t < a) rhs[t] -= bp[(size_t)t * ms + a] * wsub[a];
    __syncthreads();
  }
  if (t == 0) {
    double ssum = 0.0;
    for (int a = 0; a < m; a++) ssum += wsub[a];
    sdenom = ssum;
  }
  __syncthreads();
  if (t < m) wcc[li[t]] = (sdenom != 0.0) ? (wsub[t] / sdenom) : 0.0;
}

// ---------------- per-sample inter-cluster assembly + output ----------------
__global__ __launch_bounds__(256) void nco_inter_kernel(
    const float* __restrict__ cov, const float* __restrict__ rets,
    const double* __restrict__ wc_all, float* __restrict__ out) {
  int j = blockIdx.x, t = threadIdx.x;
  const float* C = cov + (size_t)j * NA * NA;
  const float* r = rets + (size_t)j * NA;

  __shared__ double wc[NC][NA];
  __shared__ double tmpL[NC][NA];
  __shared__ double interA[NC][NC];
  __shared__ double interb[NC];
  __shared__ double wi[NC];

  for (int c = 0; c < NC; c++) wc[c][t] = wc_all[((size_t)j * NC + c) * NA + t];
  __syncthreads();

  {
    double tcol[NC];
#pragma unroll
    for (int c = 0; c < NC; c++) tcol[c] = 0.0;
    for (int p = 0; p < NA; p++) {
      double cv = (double)C[(size_t)p * NA + t];
#pragma unroll
      for (int c = 0; c < NC; c++) tcol[c] += wc[c][p] * cv;
    }
#pragma unroll
    for (int c = 0; c < NC; c++) tmpL[c][t] = tcol[c];
  }
  __syncthreads();

  if (t < NC * NC) {
    int c = t / NC, c2 = t % NC;
    double s = 0.0;
    for (int q = 0; q < NA; q++) s += tmpL[c][q] * wc[c2][q];
    interA[c][c2] = s;
  }
  if (t >= 64 && t < 64 + NC) {
    int c = t - 64;
    double s = 0.0;
    for (int p = 0; p < NA; p++) s += wc[c][p] * (double)r[p];
    interb[c] = s;
  }
  __syncthreads();

  if (t == 0) {
    double A[NC][NC], bb[NC];
    for (int a = 0; a < NC; a++) {
      bb[a] = interb[a];
      for (int q = 0; q < NC; q++) A[a][q] = interA[a][q];
    }
    for (int k = 0; k < NC; k++) {
      int p = k; double mx = fabs(A[k][k]);
      for (int i2 = k + 1; i2 < NC; i2++) {
        double v = fabs(A[i2][k]);
        if (v > mx) { mx = v; p = i2; }
      }
      if (p != k) {
        for (int q = 0; q < NC; q++) { double tv = A[k][q]; A[k][q] = A[p][q]; A[p][q] = tv; }
        double tb = bb[k]; bb[k] = bb[p]; bb[p] = tb;
      }
      for (int i2 = k + 1; i2 < NC; i2++) {
        double f = A[i2][k] / A[k][k];
        bb[i2] -= f * bb[k];
        for (int q = k + 1; q < NC; q++) A[i2][q] -= f * A[k][q];
      }
    }
    double w[NC];
    for (int a = NC - 1; a >= 0; a--) {
      double s = bb[a];
      for (int q = a + 1; q < NC; q++) s -= A[a][q] * w[q];
      w[a] = s / A[a][a];
    }
    double ssum = 0.0;
    for (int a = 0; a < NC; a++) ssum += w[a];
    for (int a = 0; a < NC; a++) wi[a] = w[a] / ssum;
  }
  __syncthreads();

  double o = 0.0;
#pragma unroll
  for (int c = 0; c < NC; c++) o += wc[c][t] * wi[c];
  out[(size_t)j * NA + t] = (float)o;
}

extern "C" void kernel_launch(void* const* d_in, const int* in_sizes, int n_in,
                              void* d_out, int out_size, void* d_ws, size_t ws_size,
                              hipStream_t stream) {
  const float* cov  = (const float*)d_in[0];
  const float* rets = (const float*)d_in[1];
  float* out = (float*)d_out;
  char* ws = (char*)d_ws;

  const size_t g_bytes = (size_t)NS * NA * NA * sizeof(double);        // 32 MiB
  double* G          = (double*)(ws);
  double* inertiaAll = (double*)(ws + g_bytes);                        // 5 KiB
  int*    ixsAll     = (int*)   (ws + g_bytes + 5120);                 // 640 KiB
  double* wc_all     = (double*)(ws + g_bytes + 5120 + 655360);        // 1 MiB
  double* gbuf_all   = G;       // alias: G dead after kmeans

  hipLaunchKernelGGL(nco_gram_kernel,   dim3(NS * 10), dim3(NA),  0, stream, cov, G);
  hipLaunchKernelGGL(nco_kmeans_kernel, dim3(NS * NI), dim3(512), 0, stream,
                     G, ixsAll, inertiaAll);
  hipLaunchKernelGGL(nco_csolve_kernel, dim3(NS * NC), dim3(NA),  0, stream,
                     cov, rets, ixsAll, inertiaAll, gbuf_all, wc_all);
  hipLaunchKernelGGL(nco_inter_kernel,  dim3(NS),      dim3(NA),  0, stream,
                     cov, rets, wc_all, out);
}